// Round 3
// baseline (330.124 us; speedup 1.0000x reference)
//
#include <hip/hip_runtime.h>

typedef unsigned short u16;
typedef unsigned int u32;
typedef __attribute__((ext_vector_type(8))) short short8;
typedef __attribute__((ext_vector_type(4))) float f32x4;

#define HID 128

static inline int cdiv(long long a, int b) { return (int)((a + b - 1) / b); }

__device__ __forceinline__ float bfbits(u32 u) { union { u32 u; float f; } c; c.u = u; return c.f; }
__device__ __forceinline__ u16 f2bf(float f) {
  union { float f; u32 u; } c; c.f = f;
  u32 u = c.u;
  return (u16)((u + 0x7fffu + ((u >> 16) & 1u)) >> 16);  // RNE
}
__device__ __forceinline__ u32 pack2bf(float a, float b) {
  return (u32)f2bf(a) | ((u32)f2bf(b) << 16);
}

// ---------- MFMA GEMM + attention epilogue: no LDS, no barrier ----------
// B-fragment comes straight from global per lane (zero inter-wave reuse ->
// staging would be pure overhead). W^T is 32KB, L1/L2-resident.
// mfma(Wfrag, Hfrag) => acc[ct][r] = xl[node row][col=ct*16+lk*4+r].
// BF16IN: hidden layers store H as bf16 (identical rounding to the old
// fp32->bf16 cvt here), halving B traffic and skipping the cvt VALU work.
template <int COUT, int HEADS, bool BF16IN>
__global__ __launch_bounds__(256) void gemm_attn_mfma(
    const void* __restrict__ HinV, const u16* __restrict__ WT,
    const float* __restrict__ attS, const float* __restrict__ attD,
    u16* __restrict__ XL, float* __restrict__ aS, float* __restrict__ aD, int n) {
  constexpr int NT = COUT / 16;    // col tiles (8 or 4)
  constexpr int C = COUT / HEADS;  // per-head channels
  constexpr int TPH = C / 16;      // tiles per head

  int t = threadIdx.x;
  int wv = t >> 6, ln = t & 63;
  int lrow = ln & 15;  // node-row within wave (= D col index)
  int lk = ln >> 4;    // k sub-chunk / D row-quad index
  int row = blockIdx.x * 64 + wv * 16 + lrow;
  bool ok = (row < n);
  int rowc = ok ? row : (n - 1);  // clamp: loads stay valid, stores guarded

  short8 bb[4];
  if (BF16IN) {
    const u16* hp = (const u16*)HinV + (size_t)rowc * HID;
#pragma unroll
    for (int kb = 0; kb < 4; ++kb)
      bb[kb] = *(const short8*)(hp + kb * 32 + lk * 8);
  } else {
    const float* hp = (const float*)HinV + (size_t)rowc * HID;
    float4 hv[8];
#pragma unroll
    for (int kb = 0; kb < 4; ++kb) {
      hv[2 * kb] = *(const float4*)(hp + kb * 32 + lk * 8);
      hv[2 * kb + 1] = *(const float4*)(hp + kb * 32 + lk * 8 + 4);
    }
#pragma unroll
    for (int kb = 0; kb < 4; ++kb) {
      union { short8 s; u32 u[4]; } pk;
      float4 h0 = hv[2 * kb], h1 = hv[2 * kb + 1];
      pk.u[0] = pack2bf(h0.x, h0.y);
      pk.u[1] = pack2bf(h0.z, h0.w);
      pk.u[2] = pack2bf(h1.x, h1.y);
      pk.u[3] = pack2bf(h1.z, h1.w);
      bb[kb] = pk.s;
    }
  }

  f32x4 acc[NT];
#pragma unroll
  for (int ct = 0; ct < NT; ++ct) acc[ct] = {0.f, 0.f, 0.f, 0.f};

#pragma unroll
  for (int kb = 0; kb < 4; ++kb) {
    const u16* wp = WT + (size_t)lrow * HID + kb * 32 + lk * 8;
#pragma unroll
    for (int ct = 0; ct < NT; ++ct) {
      short8 aw = *(const short8*)(wp + (size_t)ct * 16 * HID);
      acc[ct] = __builtin_amdgcn_mfma_f32_16x16x32_bf16(aw, bb[kb], acc[ct], 0, 0, 0);
    }
  }

  // ---- attention epilogue: per-row per-head dots from acc registers ----
  float pS[HEADS], pD[HEADS];
#pragma unroll
  for (int h = 0; h < HEADS; ++h) { pS[h] = 0.f; pD[h] = 0.f; }
#pragma unroll
  for (int ct = 0; ct < NT; ++ct) {
    float4 sv = *(const float4*)(attS + ct * 16 + lk * 4);
    float4 dv = *(const float4*)(attD + ct * 16 + lk * 4);
    int h = ct / TPH;
    pS[h] += acc[ct][0] * sv.x + acc[ct][1] * sv.y + acc[ct][2] * sv.z + acc[ct][3] * sv.w;
    pD[h] += acc[ct][0] * dv.x + acc[ct][1] * dv.y + acc[ct][2] * dv.z + acc[ct][3] * dv.w;
  }
#pragma unroll
  for (int h = 0; h < HEADS; ++h) {
    pS[h] += __shfl_xor(pS[h], 16);
    pS[h] += __shfl_xor(pS[h], 32);
    pD[h] += __shfl_xor(pD[h], 16);
    pD[h] += __shfl_xor(pD[h], 32);
  }
  if (lk == 0 && ok) {
    if (HEADS == 4) {
      *(float4*)(aS + (size_t)row * 4) = make_float4(pS[0], pS[1], pS[2], pS[3]);
      *(float4*)(aD + (size_t)row * 4) = make_float4(pD[0], pD[1], pD[2], pD[3]);
    } else {
      aS[row] = pS[0];
      aD[row] = pD[0];
    }
  }

  // ---- XL store: 4 consecutive cols per lane -> packed uint2 ----
  if (ok) {
    u32* Xp = (u32*)XL + (size_t)row * (COUT / 2);
#pragma unroll
    for (int ct = 0; ct < NT; ++ct) {
      *(uint2*)(Xp + ct * 8 + lk * 2) =
          make_uint2(pack2bf(acc[ct][0], acc[ct][1]), pack2bf(acc[ct][2], acc[ct][3]));
    }
  }
}

// ============ bucket-sort CSR build ============
#define PSTR 16  // padding stride (ints) for per-bucket counters

// hist for 3 layers (blockIdx.y 0..2) + W pre-transpose plane (blockIdx.y==3)
__global__ __launch_bounds__(256) void bucket_hist_prep(
    const int* __restrict__ ei, int* __restrict__ cntP, int e4, int rem, int E, int NB,
    const float* __restrict__ W1, const float* __restrict__ W2,
    const float* __restrict__ W3, u16* __restrict__ wt1, u16* __restrict__ wt2,
    u16* __restrict__ wt3) {
  if (blockIdx.y == 3) {
    int bx = blockIdx.x;
    if (bx >= 160) return;
    int y = (bx >= 128) ? 2 : (bx >= 64 ? 1 : 0);
    int b0 = (y == 0) ? 0 : ((y == 1) ? 64 : 128);
    const float* W = (y == 0) ? W1 : ((y == 1) ? W2 : W3);
    u16* WT = (y == 0) ? wt1 : ((y == 1) ? wt2 : wt3);
    int cout = (y == 2) ? 64 : 128;
    int idx = (bx - b0) * 256 + threadIdx.x;
    if (idx < 128 * cout) {
      int k = idx / cout, c = idx - k * cout;
      WT[c * 128 + k] = f2bf(W[idx]);
    }
    return;
  }
  int L = blockIdx.y;
  const int* dst = ei + (size_t)(2 * L + 1) * E;
  __shared__ int cnt[256];
  int t = threadIdx.x;
  cnt[t] = 0;
  __syncthreads();
  int gbase = blockIdx.x * 1024 + t;
#pragma unroll
  for (int u = 0; u < 4; ++u) {
    int g = gbase + u * 256;
    if (g < e4) {
      int4 d = *(const int4*)(dst + g * 4);
      atomicAdd(&cnt[d.x >> 8], 1);
      atomicAdd(&cnt[d.y >> 8], 1);
      atomicAdd(&cnt[d.z >> 8], 1);
      atomicAdd(&cnt[d.w >> 8], 1);
    }
  }
  if (blockIdx.x == 0 && t < rem) atomicAdd(&cnt[dst[e4 * 4 + t] >> 8], 1);
  __syncthreads();
  int c = cnt[t];
  if (t < NB && c > 0) atomicAdd(&cntP[(L * NB + t) * PSTR], c);
}

__global__ __launch_bounds__(256) void bucket_scan(const int* __restrict__ cntP,
                                                   int* __restrict__ bucketOff,
                                                   int* __restrict__ curP, int NB, int E) {
  int L = blockIdx.x;
  int t = threadIdx.x;
  int lane = t & 63, wid = t >> 6;
  __shared__ int wpart[4];
  int v = (t < NB) ? cntP[(L * NB + t) * PSTR] : 0;
  int inc = v;
#pragma unroll
  for (int off = 1; off < 64; off <<= 1) {
    int w = __shfl_up(inc, (unsigned)off, 64);
    if (lane >= off) inc += w;
  }
  if (lane == 63) wpart[wid] = inc;
  __syncthreads();
  if (t == 0) {
    int a = 0;
#pragma unroll
    for (int k = 0; k < 4; ++k) { int tmp = wpart[k]; wpart[k] = a; a += tmp; }
  }
  __syncthreads();
  int ex = wpart[wid] + inc - v;
  if (t < NB) {
    bucketOff[L * (NB + 1) + t] = ex;
    curP[(L * NB + t) * PSTR] = ex;
  }
  if (t == 0) bucketOff[L * (NB + 1) + NB] = E;
}

__global__ __launch_bounds__(256) void bucket_scatter(const int* __restrict__ ei,
                                                      int* __restrict__ curP,
                                                      int2* __restrict__ pairsAll,
                                                      int e4, int rem, int E, int NB) {
  int L = blockIdx.y;
  const int* src = ei + (size_t)(2 * L) * E;
  const int* dst = src + E;
  int2* pairs = pairsAll + (size_t)L * E;
  __shared__ int cnt[256];
  __shared__ int baseS[256];
  int t = threadIdx.x;
  cnt[t] = 0;
  __syncthreads();

  int gbase = blockIdx.x * 1024 + t;
  int4 dv[4], sv[4];
  bool val[4];
#pragma unroll
  for (int u = 0; u < 4; ++u) {
    int g = gbase + u * 256;
    val[u] = (g < e4);
    if (val[u]) {
      dv[u] = *(const int4*)(dst + g * 4);
      sv[u] = *(const int4*)(src + g * 4);
      atomicAdd(&cnt[dv[u].x >> 8], 1);
      atomicAdd(&cnt[dv[u].y >> 8], 1);
      atomicAdd(&cnt[dv[u].z >> 8], 1);
      atomicAdd(&cnt[dv[u].w >> 8], 1);
    }
  }
  int tailS = 0, tailD = 0;
  bool hasTail = (blockIdx.x == 0 && t < rem);
  if (hasTail) {
    tailD = dst[e4 * 4 + t];
    tailS = src[e4 * 4 + t];
    atomicAdd(&cnt[tailD >> 8], 1);
  }
  __syncthreads();
  int c = cnt[t];
  if (t < NB && c > 0) baseS[t] = atomicAdd(&curP[(L * NB + t) * PSTR], c);
  __syncthreads();
  cnt[t] = 0;  // reuse as local offset
  __syncthreads();
#pragma unroll
  for (int u = 0; u < 4; ++u) {
    if (val[u]) {
      int b, p;
      b = dv[u].x >> 8; p = atomicAdd(&cnt[b], 1); pairs[baseS[b] + p] = make_int2(sv[u].x, dv[u].x);
      b = dv[u].y >> 8; p = atomicAdd(&cnt[b], 1); pairs[baseS[b] + p] = make_int2(sv[u].y, dv[u].y);
      b = dv[u].z >> 8; p = atomicAdd(&cnt[b], 1); pairs[baseS[b] + p] = make_int2(sv[u].z, dv[u].z);
      b = dv[u].w >> 8; p = atomicAdd(&cnt[b], 1); pairs[baseS[b] + p] = make_int2(sv[u].w, dv[u].w);
    }
  }
  if (hasTail) {
    int b = tailD >> 8;
    int p = atomicAdd(&cnt[b], 1);
    pairs[baseS[b] + p] = make_int2(tailS, tailD);
  }
}

__global__ __launch_bounds__(256) void csr_finalize(const int2* __restrict__ pairsAll,
                                                    const int* __restrict__ bucketOff,
                                                    int* __restrict__ indptrAll,
                                                    int* __restrict__ srcIdxAll,
                                                    int N, int E, int NB) {
  int L = blockIdx.y, b = blockIdx.x;
  const int2* pairs = pairsAll + (size_t)L * E;
  int* indptr = indptrAll + (size_t)L * (N + 1);
  int* srcL = srcIdxAll + (size_t)L * (E + N);
  int base = b << 8;
  int nodes = min(256, N - base);
  int p0 = bucketOff[L * (NB + 1) + b];
  int p1 = bucketOff[L * (NB + 1) + b + 1];

  __shared__ int cnt[256];
  __shared__ int wpart[4];
  int t = threadIdx.x;
  int lane = t & 63, wid = t >> 6;
  cnt[t] = 0;
  __syncthreads();

  for (int i = p0 + t; i < p1; i += 256) atomicAdd(&cnt[pairs[i].y - base], 1);
  __syncthreads();

  int v = (t < nodes) ? cnt[t] + 1 : 0;
  int inc = v;
#pragma unroll
  for (int off = 1; off < 64; off <<= 1) {
    int w = __shfl_up(inc, (unsigned)off, 64);
    if (lane >= off) inc += w;
  }
  if (lane == 63) wpart[wid] = inc;
  __syncthreads();
  if (t == 0) {
    int a = 0;
#pragma unroll
    for (int k = 0; k < 4; ++k) { int tmp = wpart[k]; wpart[k] = a; a += tmp; }
  }
  __syncthreads();
  int ex = wpart[wid] + inc - v;
  __syncthreads();
  if (t < nodes) {
    int segStart = p0 + base + ex;
    indptr[base + t] = segStart;
    srcL[segStart] = base + t;
    cnt[t] = segStart + 1;
  }
  if (b == NB - 1 && t == 0) indptr[N] = E + N;
  __syncthreads();

  for (int i = p0 + t; i < p1; i += 256) {
    int2 pr = pairs[i];
    int p = atomicAdd(&cnt[pr.y - base], 1);
    srcL[p] = pr.x;
  }
}

// ---------- aggregation: 16-lane (or 8-lane) group per node, ZERO shuffles ----
// Each lane owns 8 output columns (one uint4 of bf16 XL per edge): softmax
// accumulation is lane-local; denominator s computed redundantly (identical)
// per lane; srcIdx[e0+k] is a broadcast load. Depth-2 gather pipeline; ~8
// waves/SIMD hide L2/L3 gather latency.
template <int COUT, int HEADS, bool RELU, bool OUTBF>
__global__ __launch_bounds__(256) void aggregate(
    const u16* __restrict__ XL, const float* __restrict__ aS, const float* __restrict__ aD,
    const int* __restrict__ indptr, const int* __restrict__ srcIdx,
    const float* __restrict__ bias, void* __restrict__ outV, int n) {
  constexpr int LPN = COUT / 8;  // lanes per node (16 or 8)
  constexpr int NPW = 64 / LPN;  // nodes per wave (4 or 8)
  constexpr int C = COUT / HEADS;

  int wid = (blockIdx.x * blockDim.x + threadIdx.x) >> 6;
  int lane = threadIdx.x & 63;
  int sub = lane / LPN;
  int cl = lane % LPN;
  int i = wid * NPW + sub;
  bool ok = (i < n);
  int ic = ok ? i : (n - 1);

  int col0 = cl * 8;
  int h = col0 / C;
  float ad = aD[(size_t)ic * HEADS + h];
  int e0 = indptr[ic], e1 = indptr[ic + 1];
  int deg = e1 - e0;  // >= 1 (self-loop)

  const u32* XL32 = (const u32*)XL;
  float s = 0.f;
  float acc[8];
#pragma unroll
  for (int v = 0; v < 8; ++v) acc[v] = 0.f;

  // preload edge 0
  int jn = srcIdx[e0];
  float an = aS[(size_t)jn * HEADS + h];
  uint4 qn = *(const uint4*)(XL32 + (size_t)jn * (COUT / 2) + cl * 4);

#pragma unroll 2
  for (int k = 0; k < deg; ++k) {
    float ac = an;
    uint4 qc = qn;
    if (k + 1 < deg) {
      int j2 = srcIdx[e0 + k + 1];
      an = aS[(size_t)j2 * HEADS + h];
      qn = *(const uint4*)(XL32 + (size_t)j2 * (COUT / 2) + cl * 4);
    }
    float l = ac + ad;
    l = (l >= 0.f) ? l : 0.2f * l;
    float el = __expf(fminf(l, 60.f));
    s += el;
    acc[0] += el * bfbits(qc.x << 16);
    acc[1] += el * bfbits(qc.x & 0xffff0000u);
    acc[2] += el * bfbits(qc.y << 16);
    acc[3] += el * bfbits(qc.y & 0xffff0000u);
    acc[4] += el * bfbits(qc.z << 16);
    acc[5] += el * bfbits(qc.z & 0xffff0000u);
    acc[6] += el * bfbits(qc.w << 16);
    acc[7] += el * bfbits(qc.w & 0xffff0000u);
  }

  if (!ok) return;
  float inv = 1.f / (s + 1e-16f);
  float o[8];
#pragma unroll
  for (int v = 0; v < 8; ++v) {
    o[v] = acc[v] * inv + bias[col0 + v];
    if (RELU) o[v] = fmaxf(o[v], 0.f);
  }
  if (OUTBF) {
    u32* op = (u32*)outV + (size_t)i * (COUT / 2) + cl * 4;
    *(uint4*)op = make_uint4(pack2bf(o[0], o[1]), pack2bf(o[2], o[3]),
                             pack2bf(o[4], o[5]), pack2bf(o[6], o[7]));
  } else {
    float* op = (float*)outV + (size_t)i * COUT + col0;
    *(float4*)op = make_float4(o[0], o[1], o[2], o[3]);
    *(float4*)(op + 4) = make_float4(o[4], o[5], o[6], o[7]);
  }
}

extern "C" void kernel_launch(void* const* d_in, const int* in_sizes, int n_in,
                              void* d_out, int out_size, void* d_ws, size_t ws_size,
                              hipStream_t stream) {
  const float* x = (const float*)d_in[0];
  const int* ei = (const int*)d_in[1];
  const float* W1 = (const float*)d_in[2];
  const float* as1 = (const float*)d_in[3];
  const float* ad1 = (const float*)d_in[4];
  const float* b1 = (const float*)d_in[5];
  const float* W2 = (const float*)d_in[6];
  const float* as2 = (const float*)d_in[7];
  const float* ad2 = (const float*)d_in[8];
  const float* b2 = (const float*)d_in[9];
  const float* W3 = (const float*)d_in[10];
  const float* as3 = (const float*)d_in[11];
  const float* ad3 = (const float*)d_in[12];
  const float* b3 = (const float*)d_in[13];

  int N = in_sizes[0] / HID;  // x is [N,128]
  int E = in_sizes[1] / 6;    // edge_indices is [3,2,E]
  int NB = cdiv(N, 256);      // buckets of 256 nodes (NB <= 256 assumed)

  char* w = (char*)d_ws;
  auto alloc = [&](size_t bytes) {
    void* q = (void*)w;
    w += (bytes + 255) & ~(size_t)255;
    return q;
  };
  u16* bufH = (u16*)alloc((size_t)N * HID * 2);   // hidden activations, bf16
  u16* bufXL = (u16*)alloc((size_t)N * HID * 2);  // post-linear features, bf16
  float* aS = (float*)alloc((size_t)N * 4 * 4);
  float* aD = (float*)alloc((size_t)N * 4 * 4);
  u16* wt1 = (u16*)alloc((size_t)128 * 128 * 2);
  u16* wt2 = (u16*)alloc((size_t)128 * 128 * 2);
  u16* wt3 = (u16*)alloc((size_t)64 * 128 * 2);
  int* cntP = (int*)alloc((size_t)3 * NB * PSTR * 4);
  int* curP = (int*)alloc((size_t)3 * NB * PSTR * 4);
  int* bucketOff = (int*)alloc((size_t)3 * (NB + 1) * 4);
  int2* pairsAll = (int2*)alloc((size_t)3 * E * 8);
  int* indptrAll = (int*)alloc((size_t)3 * (N + 1) * 4);
  int* srcIdxAll = (int*)alloc((size_t)3 * (E + N) * 4);

  int e4 = E >> 2, rem = E & 3;
  int gx = cdiv(e4, 1024);  // 4096 edges per block
  int gxh = (gx > 160) ? gx : 160;  // prep plane needs 160 blocks

  // ---- CSR build (3 layers) + W transpose fused into hist launch ----
  hipMemsetAsync(cntP, 0, (size_t)3 * NB * PSTR * 4, stream);
  {
    dim3 g(gxh, 4);
    bucket_hist_prep<<<g, 256, 0, stream>>>(ei, cntP, e4, rem, E, NB,
                                            W1, W2, W3, wt1, wt2, wt3);
  }
  bucket_scan<<<3, 256, 0, stream>>>(cntP, bucketOff, curP, NB, E);
  {
    dim3 g(gx, 3);
    bucket_scatter<<<g, 256, 0, stream>>>(ei, curP, pairsAll, e4, rem, E, NB);
  }
  {
    dim3 g(NB, 3);
    csr_finalize<<<g, 256, 0, stream>>>(pairsAll, bucketOff, indptrAll, srcIdxAll, N, E, NB);
  }

  // ---- layer 1 (fp32 input) ----
  gemm_attn_mfma<128, 4, false><<<cdiv(N, 64), 256, 0, stream>>>(
      x, wt1, as1, ad1, bufXL, aS, aD, N);
  aggregate<128, 4, true, true><<<cdiv(N, 16), 256, 0, stream>>>(
      bufXL, aS, aD, indptrAll, srcIdxAll, b1, bufH, N);
  // ---- layer 2 (bf16 hidden) ----
  gemm_attn_mfma<128, 4, true><<<cdiv(N, 64), 256, 0, stream>>>(
      bufH, wt2, as2, ad2, bufXL, aS, aD, N);
  aggregate<128, 4, true, true><<<cdiv(N, 16), 256, 0, stream>>>(
      bufXL, aS, aD, indptrAll + (N + 1), srcIdxAll + (size_t)(E + N), b2, bufH, N);
  // ---- layer 3 (bf16 hidden, fp32 out) ----
  gemm_attn_mfma<64, 1, true><<<cdiv(N, 64), 256, 0, stream>>>(
      bufH, wt3, as3, ad3, bufXL, aS, aD, N);
  aggregate<64, 1, false, false><<<cdiv(N, 32), 256, 0, stream>>>(
      bufXL, aS, aD, indptrAll + 2 * (N + 1), srcIdxAll + (size_t)2 * (E + N), b3,
      d_out, N);
}

// Round 5
// 323.453 us; speedup vs baseline: 1.0206x; 1.0206x over previous
//
#include <hip/hip_runtime.h>

typedef unsigned short u16;
typedef unsigned int u32;
typedef __attribute__((ext_vector_type(8))) short short8;
typedef __attribute__((ext_vector_type(4))) float f32x4;

#define HID 128

static inline int cdiv(long long a, int b) { return (int)((a + b - 1) / b); }

__device__ __forceinline__ float bfbits(u32 u) { union { u32 u; float f; } c; c.u = u; return c.f; }
__device__ __forceinline__ u16 f2bf(float f) {
  union { float f; u32 u; } c; c.f = f;
  u32 u = c.u;
  return (u16)((u + 0x7fffu + ((u >> 16) & 1u)) >> 16);  // RNE
}
__device__ __forceinline__ u32 pack2bf(float a, float b) {
  return (u32)f2bf(a) | ((u32)f2bf(b) << 16);
}

// ---------- MFMA GEMM + attention epilogue (device body, no LDS/barrier) ----
// B-fragment straight from global per lane (zero inter-wave reuse). W^T is
// 32KB, L1/L2-resident. mfma(Wfrag,Hfrag) => acc[ct][r] = xl[row][ct*16+lk*4+r].
template <int COUT, int HEADS, bool BF16IN>
__device__ __forceinline__ void gemm_body(
    int bx, int t, const void* __restrict__ HinV, const u16* __restrict__ WT,
    const float* __restrict__ attS, const float* __restrict__ attD,
    u16* __restrict__ XL, float* __restrict__ aS, float* __restrict__ aD, int n) {
  constexpr int NT = COUT / 16;    // col tiles (8 or 4)
  constexpr int C = COUT / HEADS;  // per-head channels
  constexpr int TPH = C / 16;      // tiles per head

  int wv = t >> 6, ln = t & 63;
  int lrow = ln & 15;  // node-row within wave (= D col index)
  int lk = ln >> 4;    // k sub-chunk / D row-quad index
  int row = bx * 64 + wv * 16 + lrow;
  bool ok = (row < n);
  int rowc = ok ? row : (n - 1);  // clamp: loads stay valid, stores guarded

  short8 bb[4];
  if (BF16IN) {
    const u16* hp = (const u16*)HinV + (size_t)rowc * HID;
#pragma unroll
    for (int kb = 0; kb < 4; ++kb)
      bb[kb] = *(const short8*)(hp + kb * 32 + lk * 8);
  } else {
    const float* hp = (const float*)HinV + (size_t)rowc * HID;
    float4 hv[8];
#pragma unroll
    for (int kb = 0; kb < 4; ++kb) {
      hv[2 * kb] = *(const float4*)(hp + kb * 32 + lk * 8);
      hv[2 * kb + 1] = *(const float4*)(hp + kb * 32 + lk * 8 + 4);
    }
#pragma unroll
    for (int kb = 0; kb < 4; ++kb) {
      union { short8 s; u32 u[4]; } pk;
      float4 h0 = hv[2 * kb], h1 = hv[2 * kb + 1];
      pk.u[0] = pack2bf(h0.x, h0.y);
      pk.u[1] = pack2bf(h0.z, h0.w);
      pk.u[2] = pack2bf(h1.x, h1.y);
      pk.u[3] = pack2bf(h1.z, h1.w);
      bb[kb] = pk.s;
    }
  }

  f32x4 acc[NT];
#pragma unroll
  for (int ct = 0; ct < NT; ++ct) acc[ct] = {0.f, 0.f, 0.f, 0.f};

#pragma unroll
  for (int kb = 0; kb < 4; ++kb) {
    const u16* wp = WT + (size_t)lrow * HID + kb * 32 + lk * 8;
#pragma unroll
    for (int ct = 0; ct < NT; ++ct) {
      short8 aw = *(const short8*)(wp + (size_t)ct * 16 * HID);
      acc[ct] = __builtin_amdgcn_mfma_f32_16x16x32_bf16(aw, bb[kb], acc[ct], 0, 0, 0);
    }
  }

  // ---- attention epilogue: per-row per-head dots from acc registers ----
  float pS[HEADS], pD[HEADS];
#pragma unroll
  for (int h = 0; h < HEADS; ++h) { pS[h] = 0.f; pD[h] = 0.f; }
#pragma unroll
  for (int ct = 0; ct < NT; ++ct) {
    float4 sv = *(const float4*)(attS + ct * 16 + lk * 4);
    float4 dv = *(const float4*)(attD + ct * 16 + lk * 4);
    int h = ct / TPH;
    pS[h] += acc[ct][0] * sv.x + acc[ct][1] * sv.y + acc[ct][2] * sv.z + acc[ct][3] * sv.w;
    pD[h] += acc[ct][0] * dv.x + acc[ct][1] * dv.y + acc[ct][2] * dv.z + acc[ct][3] * dv.w;
  }
#pragma unroll
  for (int h = 0; h < HEADS; ++h) {
    pS[h] += __shfl_xor(pS[h], 16);
    pS[h] += __shfl_xor(pS[h], 32);
    pD[h] += __shfl_xor(pD[h], 16);
    pD[h] += __shfl_xor(pD[h], 32);
  }
  if (lk == 0 && ok) {
    if (HEADS == 4) {
      *(float4*)(aS + (size_t)row * 4) = make_float4(pS[0], pS[1], pS[2], pS[3]);
      *(float4*)(aD + (size_t)row * 4) = make_float4(pD[0], pD[1], pD[2], pD[3]);
    } else {
      aS[row] = pS[0];
      aD[row] = pD[0];
    }
  }

  // ---- XL store: 4 consecutive cols per lane -> packed uint2 ----
  if (ok) {
    u32* Xp = (u32*)XL + (size_t)row * (COUT / 2);
#pragma unroll
    for (int ct = 0; ct < NT; ++ct) {
      *(uint2*)(Xp + ct * 8 + lk * 2) =
          make_uint2(pack2bf(acc[ct][0], acc[ct][1]), pack2bf(acc[ct][2], acc[ct][3]));
    }
  }
}

template <int COUT, int HEADS, bool BF16IN>
__global__ __launch_bounds__(256) void gemm_attn_mfma(
    const void* __restrict__ HinV, const u16* __restrict__ WT,
    const float* __restrict__ attS, const float* __restrict__ attD,
    u16* __restrict__ XL, float* __restrict__ aS, float* __restrict__ aD, int n) {
  gemm_body<COUT, HEADS, BF16IN>(blockIdx.x, threadIdx.x, HinV, WT, attS, attD,
                                 XL, aS, aD, n);
}

// ============ bucket-sort CSR build ============
#define PSTR 16  // padding stride (ints) for per-bucket counters

// planes: y=0..2 hist per layer, y=3 W pre-transpose (NO consumers of wt in
// this launch -- the layer-1 gemm reads wt1 one launch later, race-free)
__global__ __launch_bounds__(256) void bucket_hist_prep(
    const int* __restrict__ ei, int* __restrict__ cntP, int e4, int rem, int E, int NB,
    const float* __restrict__ W1, const float* __restrict__ W2,
    const float* __restrict__ W3, u16* __restrict__ wt1, u16* __restrict__ wt2,
    u16* __restrict__ wt3) {
  if (blockIdx.y == 3) {
    int bx = blockIdx.x;
    if (bx >= 160) return;
    int y = (bx >= 128) ? 2 : (bx >= 64 ? 1 : 0);
    int b0 = (y == 0) ? 0 : ((y == 1) ? 64 : 128);
    const float* W = (y == 0) ? W1 : ((y == 1) ? W2 : W3);
    u16* WT = (y == 0) ? wt1 : ((y == 1) ? wt2 : wt3);
    int cout = (y == 2) ? 64 : 128;
    int idx = (bx - b0) * 256 + threadIdx.x;
    if (idx < 128 * cout) {
      int k = idx / cout, c = idx - k * cout;
      WT[c * 128 + k] = f2bf(W[idx]);
    }
    return;
  }
  int L = blockIdx.y;
  const int* dst = ei + (size_t)(2 * L + 1) * E;
  __shared__ int cnt[256];
  int t = threadIdx.x;
  cnt[t] = 0;
  __syncthreads();
  int gbase = blockIdx.x * 1024 + t;
#pragma unroll
  for (int u = 0; u < 4; ++u) {
    int g = gbase + u * 256;
    if (g < e4) {
      int4 d = *(const int4*)(dst + g * 4);
      atomicAdd(&cnt[d.x >> 8], 1);
      atomicAdd(&cnt[d.y >> 8], 1);
      atomicAdd(&cnt[d.z >> 8], 1);
      atomicAdd(&cnt[d.w >> 8], 1);
    }
  }
  if (blockIdx.x == 0 && t < rem) atomicAdd(&cnt[dst[e4 * 4 + t] >> 8], 1);
  __syncthreads();
  int c = cnt[t];
  if (t < NB && c > 0) atomicAdd(&cntP[(L * NB + t) * PSTR], c);
}

__global__ __launch_bounds__(256) void bucket_scan(const int* __restrict__ cntP,
                                                   int* __restrict__ bucketOff,
                                                   int* __restrict__ curP, int NB, int E) {
  int L = blockIdx.x;
  int t = threadIdx.x;
  int lane = t & 63, wid = t >> 6;
  __shared__ int wpart[4];
  int v = (t < NB) ? cntP[(L * NB + t) * PSTR] : 0;
  int inc = v;
#pragma unroll
  for (int off = 1; off < 64; off <<= 1) {
    int w = __shfl_up(inc, (unsigned)off, 64);
    if (lane >= off) inc += w;
  }
  if (lane == 63) wpart[wid] = inc;
  __syncthreads();
  if (t == 0) {
    int a = 0;
#pragma unroll
    for (int k = 0; k < 4; ++k) { int tmp = wpart[k]; wpart[k] = a; a += tmp; }
  }
  __syncthreads();
  int ex = wpart[wid] + inc - v;
  if (t < NB) {
    bucketOff[L * (NB + 1) + t] = ex;
    curP[(L * NB + t) * PSTR] = ex;
  }
  if (t == 0) bucketOff[L * (NB + 1) + NB] = E;
}

// pairs packed: (dst & 0xff) << 24 | src   (requires N < 2^24)
// plane y==3: layer-1 GEMM (wt1 was written by the PREVIOUS launch -- safe)
__global__ __launch_bounds__(256) void bucket_scatter_gemm(
    const int* __restrict__ ei, int* __restrict__ curP, u32* __restrict__ pairsAll,
    int e4, int rem, int E, int NB,
    const float* __restrict__ x, const u16* __restrict__ wt1,
    const float* __restrict__ as1, const float* __restrict__ ad1,
    u16* __restrict__ XL, float* __restrict__ aS, float* __restrict__ aD,
    int n, int ngb) {
  if (blockIdx.y == 3) {
    if ((int)blockIdx.x < ngb)
      gemm_body<128, 4, false>(blockIdx.x, threadIdx.x, x, wt1, as1, ad1, XL, aS, aD, n);
    return;
  }
  int L = blockIdx.y;
  const int* src = ei + (size_t)(2 * L) * E;
  const int* dst = src + E;
  u32* pairs = pairsAll + (size_t)L * E;
  __shared__ int cnt[256];
  __shared__ int baseS[256];
  int t = threadIdx.x;
  cnt[t] = 0;
  __syncthreads();

  int gbase = blockIdx.x * 1024 + t;
  int4 dv[4], sv[4];
  bool val[4];
#pragma unroll
  for (int u = 0; u < 4; ++u) {
    int g = gbase + u * 256;
    val[u] = (g < e4);
    if (val[u]) {
      dv[u] = *(const int4*)(dst + g * 4);
      sv[u] = *(const int4*)(src + g * 4);
      atomicAdd(&cnt[dv[u].x >> 8], 1);
      atomicAdd(&cnt[dv[u].y >> 8], 1);
      atomicAdd(&cnt[dv[u].z >> 8], 1);
      atomicAdd(&cnt[dv[u].w >> 8], 1);
    }
  }
  int tailS = 0, tailD = 0;
  bool hasTail = (blockIdx.x == 0 && t < rem);
  if (hasTail) {
    tailD = dst[e4 * 4 + t];
    tailS = src[e4 * 4 + t];
    atomicAdd(&cnt[tailD >> 8], 1);
  }
  __syncthreads();
  int c = cnt[t];
  if (t < NB && c > 0) baseS[t] = atomicAdd(&curP[(L * NB + t) * PSTR], c);
  __syncthreads();
  cnt[t] = 0;  // reuse as local offset
  __syncthreads();
#pragma unroll
  for (int u = 0; u < 4; ++u) {
    if (val[u]) {
      int b, p;
      b = dv[u].x >> 8; p = atomicAdd(&cnt[b], 1);
      pairs[baseS[b] + p] = ((u32)(dv[u].x & 0xff) << 24) | (u32)sv[u].x;
      b = dv[u].y >> 8; p = atomicAdd(&cnt[b], 1);
      pairs[baseS[b] + p] = ((u32)(dv[u].y & 0xff) << 24) | (u32)sv[u].y;
      b = dv[u].z >> 8; p = atomicAdd(&cnt[b], 1);
      pairs[baseS[b] + p] = ((u32)(dv[u].z & 0xff) << 24) | (u32)sv[u].z;
      b = dv[u].w >> 8; p = atomicAdd(&cnt[b], 1);
      pairs[baseS[b] + p] = ((u32)(dv[u].w & 0xff) << 24) | (u32)sv[u].w;
    }
  }
  if (hasTail) {
    int b = tailD >> 8;
    int p = atomicAdd(&cnt[b], 1);
    pairs[baseS[b] + p] = ((u32)(tailD & 0xff) << 24) | (u32)tailS;
  }
}

__global__ __launch_bounds__(256) void csr_finalize(const u32* __restrict__ pairsAll,
                                                    const int* __restrict__ bucketOff,
                                                    int* __restrict__ indptrAll,
                                                    int* __restrict__ srcIdxAll,
                                                    int N, int E, int NB) {
  int L = blockIdx.y, b = blockIdx.x;
  const u32* pairs = pairsAll + (size_t)L * E;
  int* indptr = indptrAll + (size_t)L * (N + 1);
  int* srcL = srcIdxAll + (size_t)L * (E + N);
  int base = b << 8;
  int nodes = min(256, N - base);
  int p0 = bucketOff[L * (NB + 1) + b];
  int p1 = bucketOff[L * (NB + 1) + b + 1];

  __shared__ int cnt[256];
  __shared__ int wpart[4];
  int t = threadIdx.x;
  int lane = t & 63, wid = t >> 6;
  cnt[t] = 0;
  __syncthreads();

  for (int i = p0 + t; i < p1; i += 256) atomicAdd(&cnt[pairs[i] >> 24], 1);
  __syncthreads();

  int v = (t < nodes) ? cnt[t] + 1 : 0;
  int inc = v;
#pragma unroll
  for (int off = 1; off < 64; off <<= 1) {
    int w = __shfl_up(inc, (unsigned)off, 64);
    if (lane >= off) inc += w;
  }
  if (lane == 63) wpart[wid] = inc;
  __syncthreads();
  if (t == 0) {
    int a = 0;
#pragma unroll
    for (int k = 0; k < 4; ++k) { int tmp = wpart[k]; wpart[k] = a; a += tmp; }
  }
  __syncthreads();
  int ex = wpart[wid] + inc - v;
  __syncthreads();
  if (t < nodes) {
    int segStart = p0 + base + ex;
    indptr[base + t] = segStart;
    srcL[segStart] = base + t;
    cnt[t] = segStart + 1;
  }
  if (b == NB - 1 && t == 0) indptr[N] = E + N;
  __syncthreads();

  for (int i = p0 + t; i < p1; i += 256) {
    u32 pk = pairs[i];
    int p = atomicAdd(&cnt[pk >> 24], 1);
    srcL[p] = (int)(pk & 0xffffffu);
  }
}

// ---------- aggregation: group-per-node, depth-4 gather pipeline ----------
// 16 (or 8) lanes per node, each owning 8 cols (one uint4 of bf16 XL/edge):
// accumulation lane-local, zero shuffles; denominator s redundant-identical
// per lane. 4 edges in flight per group (rotating statically-indexed slots)
// to cover L2/L3 gather latency; 8 waves/SIMD pinned. Consume order is
// strictly sequential in k -> summation order identical to the simple loop.
template <int COUT, int HEADS, bool RELU, bool OUTBF>
__global__ __launch_bounds__(256, 8) void aggregate(
    const u16* __restrict__ XL, const float* __restrict__ aS, const float* __restrict__ aD,
    const int* __restrict__ indptr, const int* __restrict__ srcIdx,
    const float* __restrict__ bias, void* __restrict__ outV, int n) {
  constexpr int LPN = COUT / 8;  // lanes per node (16 or 8)
  constexpr int NPW = 64 / LPN;  // nodes per wave (4 or 8)
  constexpr int C = COUT / HEADS;
  constexpr int D = 4;           // pipeline depth (edges in flight)

  int wid = (blockIdx.x * blockDim.x + threadIdx.x) >> 6;
  int lane = threadIdx.x & 63;
  int sub = lane / LPN;
  int cl = lane % LPN;
  int i = wid * NPW + sub;
  bool ok = (i < n);
  int ic = ok ? i : (n - 1);

  int col0 = cl * 8;
  int h = col0 / C;
  float ad = aD[(size_t)ic * HEADS + h];
  int e0 = indptr[ic];
  int deg = indptr[ic + 1] - e0;  // >= 1 (self-loop present)

  const u32* XL32 = (const u32*)XL;
  float s = 0.f;
  float acc[8];
#pragma unroll
  for (int v = 0; v < 8; ++v) acc[v] = 0.f;

  auto fetch = [&](int k, float& av, uint4& q) {
    int kk = (k < deg) ? k : 0;          // clamp to first edge (L1-hot)
    int j = srcIdx[e0 + kk];             // broadcast within group
    av = aS[(size_t)j * HEADS + h];
    q = *(const uint4*)(XL32 + (size_t)j * (COUT / 2) + cl * 4);
  };
  auto consume = [&](int k, float av, const uint4& q) {
    if (k >= deg) return;
    float l = av + ad;
    l = (l >= 0.f) ? l : 0.2f * l;
    float el = __expf(fminf(l, 60.f));
    s += el;
    acc[0] += el * bfbits(q.x << 16);
    acc[1] += el * bfbits(q.x & 0xffff0000u);
    acc[2] += el * bfbits(q.y << 16);
    acc[3] += el * bfbits(q.y & 0xffff0000u);
    acc[4] += el * bfbits(q.z << 16);
    acc[5] += el * bfbits(q.z & 0xffff0000u);
    acc[6] += el * bfbits(q.w << 16);
    acc[7] += el * bfbits(q.w & 0xffff0000u);
  };

  float aP[D];
  uint4 qP[D];
#pragma unroll
  for (int j = 0; j < D; ++j) fetch(j, aP[j], qP[j]);

  for (int k0 = 0; k0 < deg; k0 += D) {
    bool more = (k0 + D < deg);  // uniform within group
#pragma unroll
    for (int j = 0; j < D; ++j) {
      float av = aP[j];
      uint4 q = qP[j];
      if (more) fetch(k0 + D + j, aP[j], qP[j]);  // issue early, consume later
      consume(k0 + j, av, q);
    }
  }

  if (!ok) return;
  float inv = 1.f / (s + 1e-16f);
  float o[8];
#pragma unroll
  for (int v = 0; v < 8; ++v) {
    o[v] = acc[v] * inv + bias[col0 + v];
    if (RELU) o[v] = fmaxf(o[v], 0.f);
  }
  if (OUTBF) {
    u32* op = (u32*)outV + (size_t)i * (COUT / 2) + cl * 4;
    *(uint4*)op = make_uint4(pack2bf(o[0], o[1]), pack2bf(o[2], o[3]),
                             pack2bf(o[4], o[5]), pack2bf(o[6], o[7]));
  } else {
    float* op = (float*)outV + (size_t)i * COUT + col0;
    *(float4*)op = make_float4(o[0], o[1], o[2], o[3]);
    *(float4*)(op + 4) = make_float4(o[4], o[5], o[6], o[7]);
  }
}

extern "C" void kernel_launch(void* const* d_in, const int* in_sizes, int n_in,
                              void* d_out, int out_size, void* d_ws, size_t ws_size,
                              hipStream_t stream) {
  const float* x = (const float*)d_in[0];
  const int* ei = (const int*)d_in[1];
  const float* W1 = (const float*)d_in[2];
  const float* as1 = (const float*)d_in[3];
  const float* ad1 = (const float*)d_in[4];
  const float* b1 = (const float*)d_in[5];
  const float* W2 = (const float*)d_in[6];
  const float* as2 = (const float*)d_in[7];
  const float* ad2 = (const float*)d_in[8];
  const float* b2 = (const float*)d_in[9];
  const float* W3 = (const float*)d_in[10];
  const float* as3 = (const float*)d_in[11];
  const float* ad3 = (const float*)d_in[12];
  const float* b3 = (const float*)d_in[13];

  int N = in_sizes[0] / HID;  // x is [N,128]
  int E = in_sizes[1] / 6;    // edge_indices is [3,2,E]
  int NB = cdiv(N, 256);      // buckets of 256 nodes (NB <= 256 assumed)

  char* w = (char*)d_ws;
  auto alloc = [&](size_t bytes) {
    void* q = (void*)w;
    w += (bytes + 255) & ~(size_t)255;
    return q;
  };
  u16* bufH = (u16*)alloc((size_t)N * HID * 2);   // hidden activations, bf16
  u16* bufXL = (u16*)alloc((size_t)N * HID * 2);  // post-linear features, bf16
  float* aS = (float*)alloc((size_t)N * 4 * 4);
  float* aD = (float*)alloc((size_t)N * 4 * 4);
  u16* wt1 = (u16*)alloc((size_t)128 * 128 * 2);
  u16* wt2 = (u16*)alloc((size_t)128 * 128 * 2);
  u16* wt3 = (u16*)alloc((size_t)64 * 128 * 2);
  int* cntP = (int*)alloc((size_t)3 * NB * PSTR * 4);
  int* curP = (int*)alloc((size_t)3 * NB * PSTR * 4);
  int* bucketOff = (int*)alloc((size_t)3 * (NB + 1) * 4);
  u32* pairsAll = (u32*)alloc((size_t)3 * E * 4);
  int* indptrAll = (int*)alloc((size_t)3 * (N + 1) * 4);
  int* srcIdxAll = (int*)alloc((size_t)3 * (E + N) * 4);

  int e4 = E >> 2, rem = E & 3;
  int gx = cdiv(e4, 1024);  // 4096 edges per block
  int ngb = cdiv(N, 64);    // gemm blocks (layer-1, fused into scatter launch)
  int gxh = (gx > 160) ? gx : 160;   // hist launch: prep plane needs 160 blocks
  int gxs = (gx > ngb) ? gx : ngb;   // scatter launch: gemm plane needs ngb

  // ---- CSR hist + W transpose (no same-launch consumers of wt) ----
  hipMemsetAsync(cntP, 0, (size_t)3 * NB * PSTR * 4, stream);
  {
    dim3 g(gxh, 4);
    bucket_hist_prep<<<g, 256, 0, stream>>>(ei, cntP, e4, rem, E, NB,
                                            W1, W2, W3, wt1, wt2, wt3);
  }
  bucket_scan<<<3, 256, 0, stream>>>(cntP, bucketOff, curP, NB, E);
  // ---- scatter + layer-1 GEMM fused (wt1 complete: previous launch) ----
  {
    dim3 g(gxs, 4);
    bucket_scatter_gemm<<<g, 256, 0, stream>>>(ei, curP, pairsAll, e4, rem, E, NB,
                                               x, wt1, as1, ad1, bufXL, aS, aD, N, ngb);
  }
  {
    dim3 g(NB, 3);
    csr_finalize<<<g, 256, 0, stream>>>(pairsAll, bucketOff, indptrAll, srcIdxAll, N, E, NB);
  }

  // ---- layer 1 (gemm already done in scatter launch) ----
  aggregate<128, 4, true, true><<<cdiv(N, 16), 256, 0, stream>>>(
      bufXL, aS, aD, indptrAll, srcIdxAll, b1, bufH, N);
  // ---- layer 2 (bf16 hidden) ----
  gemm_attn_mfma<128, 4, true><<<cdiv(N, 64), 256, 0, stream>>>(
      bufH, wt2, as2, ad2, bufXL, aS, aD, N);
  aggregate<128, 4, true, true><<<cdiv(N, 16), 256, 0, stream>>>(
      bufXL, aS, aD, indptrAll + (N + 1), srcIdxAll + (size_t)(E + N), b2, bufH, N);
  // ---- layer 3 (bf16 hidden, fp32 out) ----
  gemm_attn_mfma<64, 1, true><<<cdiv(N, 64), 256, 0, stream>>>(
      bufH, wt3, as3, ad3, bufXL, aS, aD, N);
  aggregate<64, 1, false, false><<<cdiv(N, 32), 256, 0, stream>>>(
      bufXL, aS, aD, indptrAll + 2 * (N + 1), srcIdxAll + (size_t)2 * (E + N), b3,
      d_out, N);
}